// Round 2
// baseline (492.982 us; speedup 1.0000x reference)
//
#include <hip/hip_runtime.h>
#include <math.h>

// ---------------------------------------------------------------------------
// SpectralConv3d + Chebyshev-Fourier correction, fp32, pruned separable DFTs.
// B=4, C=O=32, H=W=D=64. Modes: kx in {0..11, 52..63} (24), ky same (24),
// kz in {0..11} (12).
// out = (1/64^3) * Re[ sum F[kx,ky,kz] * w^(kx h + ky w + kz d) * c_kz ]
//       + corr_scale * corr[b,o,d],  c_0 = 1, c_kz = 2 (kz>=1).
//
// R1: DFT symmetries: z-stage real-input pairing d<->64-d; fwd y/x conjugate
//     output pairs (a, 24-a); inv_x output pairing h<->64-h; inv_yz E/O.
// R2: E/O pairing along the SUMMATION axis everywhere:
//  - fwd y/x stages: pair w<->64-w (conj twiddle). One tw read feeds both
//    outputs of both pair members: inner loop 64 -> 31 iters + 2 edge terms.
//  - inv_x: input-mode pairs ax<->24-ax (conj twiddle) composed with the
//    output pairing: 24 -> 11 pairs + 2 specials, one tw read per pair.
//  - k_mlp: unroll 8 to keep 8 L2 loads in flight (1 block/CU, latency-bound).
// ---------------------------------------------------------------------------

static __device__ __forceinline__ void fill_tw(float2* tw, int tid, int nthr) {
    // tw[m] = (cos(2 pi m / 64), sin(2 pi m / 64))
    for (int m = tid; m < 64; m += nthr) {
        float s, c;
        sincosf((float)m * 0.09817477042468103f, &s, &c);
        tw[m] = make_float2(c, s);
    }
}

// ---------------------------------------------------------------------------
// Kernel 1: fused forward DFT along D (64->12) and W (64->24).
// grid = B*C*H = 8192 blocks, 256 threads. X2[(bc*64+h)*288 + a*12 + kz]
// ---------------------------------------------------------------------------
__global__ __launch_bounds__(256) void k_fwd_zy(const float* __restrict__ x,
                                                float2* __restrict__ X2) {
    __shared__ float xt[64 * 68];        // [w][d], pad 68 to break conflicts
    __shared__ float2 z1[64 * 12];       // [w][kz]
    __shared__ float2 tw[64];
    const int tid = threadIdx.x;
    const int blk = blockIdx.x;          // (b*32+c)*64 + h
    fill_tw(tw, tid, 256);
    const float4* xrow4 = (const float4*)(x + (size_t)blk * 4096);
    for (int r = 0; r < 4; ++r) {
        int i4 = r * 256 + tid;          // 1024 float4 = 4096 floats
        int w = i4 >> 4, d4 = (i4 & 15) << 2;
        float4 v = xrow4[i4];
        *(float4*)&xt[w * 68 + d4] = v;
    }
    __syncthreads();
    // z-stage with real-input symmetry d <-> 64-d:
    // X[k] = x[0] + (-1)^k x[32]
    //      + sum_{d=1}^{31} (x[d]+x[64-d]) cos - i (x[d]-x[64-d]) sin
    {
        const int w = tid >> 2, kz0 = (tid & 3) * 3;
        const float* xr = &xt[w * 68];
        const float x0v = xr[0], x32v = xr[32];
        const float sg = (kz0 & 1) ? -x32v : x32v;   // (-1)^kz0 * x32
        float2 a0 = make_float2(x0v + sg, 0.f);      // k = kz0
        float2 a1 = make_float2(x0v - sg, 0.f);      // k = kz0+1 (opposite parity)
        float2 a2 = make_float2(x0v + sg, 0.f);      // k = kz0+2 (same parity)
        for (int d = 1; d < 32; ++d) {
            float xa = xr[d], xb = xr[64 - d];
            float e = xa + xb, o = xa - xb;
            float2 t0 = tw[(kz0 * d) & 63];
            float2 t1 = tw[((kz0 + 1) * d) & 63];
            float2 t2 = tw[((kz0 + 2) * d) & 63];
            a0.x += e * t0.x; a0.y -= o * t0.y;
            a1.x += e * t1.x; a1.y -= o * t1.y;
            a2.x += e * t2.x; a2.y -= o * t2.y;
        }
        z1[w * 12 + kz0]     = a0;
        z1[w * 12 + kz0 + 1] = a1;
        z1[w * 12 + kz0 + 2] = a2;
    }
    __syncthreads();
    // y-stage: output pairs (ky=ap, ky=64-ap) AND summation pairs w<->64-w.
    // E = z_w + z_{64-w}, O = z_w - z_{64-w}, t = (c,s) = tw[ap*w]:
    //   A  (ky=ap):    += c*E - i s O -> Re: c*Ex + s*Oy, Im: c*Ey - s*Ox
    //   Bc (ky=64-ap): += c*E + i s O -> Re: c*Ex - s*Oy, Im: c*Ey + s*Ox
    float2* xout = X2 + (size_t)blk * 288;
    if (tid < 156) {                     // 13 ap values * 12 kz
        const int ap = tid / 12, kz = tid - (tid / 12) * 12;
        const float2 zw0 = z1[kz];              // w = 0, t = (1,0)
        const float2 zw32 = z1[32 * 12 + kz];   // w = 32, t = (-1)^ap
        const float sg = (ap & 1) ? -1.f : 1.f;
        float2 A  = make_float2(zw0.x + sg * zw32.x, zw0.y + sg * zw32.y);
        float2 Bc = A;
        for (int w = 1; w < 32; ++w) {
            float2 za = z1[w * 12 + kz];
            float2 zb = z1[(64 - w) * 12 + kz];
            float Ex = za.x + zb.x, Ey = za.y + zb.y;
            float Ox = za.x - zb.x, Oy = za.y - zb.y;
            float2 t = tw[(ap * w) & 63];
            A.x  += t.x * Ex + t.y * Oy;  A.y  += t.x * Ey - t.y * Ox;
            Bc.x += t.x * Ex - t.y * Oy;  Bc.y += t.x * Ey + t.y * Ox;
        }
        if (ap <= 11) xout[ap * 12 + kz] = A;
        if (ap >= 1)  xout[(24 - ap) * 12 + kz] = Bc;
    }
}

// ---------------------------------------------------------------------------
// Kernel 2: forward DFT along H (64->24), conjugate-mode + summation pairing.
// grid = B*C*24 = 3072, 256 threads. X3[bc*6912 + ax*288 + ay*12 + kz]
// ---------------------------------------------------------------------------
__global__ __launch_bounds__(256) void k_fwd_x(const float2* __restrict__ X2,
                                               float2* __restrict__ X3) {
    __shared__ float2 s2[64 * 12];       // [h][kz]
    __shared__ float2 tw[64];
    const int tid = threadIdx.x;
    const int blk = blockIdx.x;
    const int ay = blk % 24, bc = blk / 24;
    fill_tw(tw, tid, 256);
    const float2* src = X2 + (size_t)bc * (64 * 288) + ay * 12;
    for (int i = tid; i < 768; i += 256) {
        int hh = i / 12, kz = i - hh * 12;
        s2[i] = src[hh * 288 + kz];
    }
    __syncthreads();
    float2* dst = X3 + (size_t)bc * 6912 + ay * 12;
    if (tid < 156) {                     // 13 ap values * 12 kz
        const int ap = tid / 12, kz = tid - (tid / 12) * 12;
        const float2 zw0 = s2[kz];              // hh = 0
        const float2 zw32 = s2[32 * 12 + kz];   // hh = 32
        const float sg = (ap & 1) ? -1.f : 1.f;
        float2 A  = make_float2(zw0.x + sg * zw32.x, zw0.y + sg * zw32.y);
        float2 Bc = A;
        for (int hh = 1; hh < 32; ++hh) {
            float2 za = s2[hh * 12 + kz];
            float2 zb = s2[(64 - hh) * 12 + kz];
            float Ex = za.x + zb.x, Ey = za.y + zb.y;
            float Ox = za.x - zb.x, Oy = za.y - zb.y;
            float2 t = tw[(ap * hh) & 63];
            A.x  += t.x * Ex + t.y * Oy;  A.y  += t.x * Ey - t.y * Ox;
            Bc.x += t.x * Ex - t.y * Oy;  Bc.y += t.x * Ey + t.y * Ox;
        }
        if (ap <= 11) dst[ap * 288 + kz] = A;
        if (ap >= 1)  dst[(24 - ap) * 288 + kz] = Bc;
    }
}

// ---------------------------------------------------------------------------
// Kernel 3: mode mixing F[b,o,m] = sum_i X3[b,i,m] * (wre + i wim)[i,o,m].
// grid = 24*24 = 576 blocks (one (ax,ay)), 384 threads = (o,kz).
// Weights streamed from global exactly once in total.
// ---------------------------------------------------------------------------
__global__ __launch_bounds__(384) void k_mix(const float2* __restrict__ X3,
                                             float2* __restrict__ F,
        const float* __restrict__ w1re, const float* __restrict__ w1im,
        const float* __restrict__ w2re, const float* __restrict__ w2im,
        const float* __restrict__ w3re, const float* __restrict__ w3im,
        const float* __restrict__ w4re, const float* __restrict__ w4im) {
    __shared__ float2 xs[128 * 12];      // [b*32+i][kz]
    const int tid = threadIdx.x;
    const int blk = blockIdx.x;
    const int ax = blk / 24, ay = blk % 24;
    const int cx = ax >= 12 ? 1 : 0, cy = ay >= 12 ? 1 : 0;
    const int m1 = ax - cx * 12, m2 = ay - cy * 12;
    const int sel = cx + cy * 2;         // 0:w1 (lo,lo) 1:w2 (hi,lo) 2:w3 (lo,hi) 3:w4
    const float* wre = sel == 0 ? w1re : sel == 1 ? w2re : sel == 2 ? w3re : w4re;
    const float* wim = sel == 0 ? w1im : sel == 1 ? w2im : sel == 2 ? w3im : w4im;
    const size_t moff = (size_t)ax * 288 + (size_t)ay * 12;
    for (int i = tid; i < 1536; i += 384) {
        int bi = i / 12, kz = i - bi * 12;
        xs[i] = X3[(size_t)bi * 6912 + moff + kz];
    }
    __syncthreads();
    const int o = tid / 12, kz = tid - (tid / 12) * 12;
    const int wbase = o * 1728 + m1 * 144 + m2 * 12 + kz;
    float2 A0 = make_float2(0.f, 0.f), A1 = A0, A2 = A0, A3 = A0;
    for (int i = 0; i < 32; ++i) {
        float wr = wre[i * 55296 + wbase];
        float wi = wim[i * 55296 + wbase];
        float2 x0 = xs[i * 12 + kz];
        float2 x1 = xs[(32 + i) * 12 + kz];
        float2 x2 = xs[(64 + i) * 12 + kz];
        float2 x3 = xs[(96 + i) * 12 + kz];
        A0.x += x0.x * wr - x0.y * wi; A0.y += x0.x * wi + x0.y * wr;
        A1.x += x1.x * wr - x1.y * wi; A1.y += x1.x * wi + x1.y * wr;
        A2.x += x2.x * wr - x2.y * wi; A2.y += x2.x * wi + x2.y * wr;
        A3.x += x3.x * wr - x3.y * wi; A3.y += x3.x * wi + x3.y * wr;
    }
    F[(size_t)(0 * 32 + o) * 6912 + moff + kz] = A0;
    F[(size_t)(1 * 32 + o) * 6912 + moff + kz] = A1;
    F[(size_t)(2 * 32 + o) * 6912 + moff + kz] = A2;
    F[(size_t)(3 * 32 + o) * 6912 + moff + kz] = A3;
}

// ---------------------------------------------------------------------------
// Kernel 4: inverse DFT along H (24->64): output pairing h <-> 64-h composed
// with input-mode pairing ax <-> 24-ax (conjugate twiddles). One tw read
// drives all four (input-pair x output-pair) contributions.
// grid = B*O*24 = 3072, 256 threads. Y1[(bo*64+h)*288 + ay*12 + kz]
// ---------------------------------------------------------------------------
__global__ __launch_bounds__(256) void k_inv_x(const float2* __restrict__ F,
                                               float2* __restrict__ Y1) {
    __shared__ float2 fs[24 * 12];
    __shared__ float2 tw[64];
    const int tid = threadIdx.x;
    const int blk = blockIdx.x;
    const int ay = blk % 24, bo = blk / 24;
    fill_tw(tw, tid, 256);
    const float2* src = F + (size_t)bo * 6912 + ay * 12;
    for (int i = tid; i < 288; i += 256) {
        int ax = i / 12, kz = i - ax * 12;
        fs[i] = src[ax * 288 + kz];
    }
    __syncthreads();
    float2* dst = Y1 + (size_t)bo * (64 * 288) + ay * 12;
    // hp in 0..32: A -> h=hp; Bc -> h=64-hp (hp in 1..31).
    // Pairs a=1..11 with 24-a (kxv=64-a): E=fa+fb, O=fa-fb, t=tw[a*hp]:
    //   A  += c*E + i s O -> Re: c*Ex - s*Oy, Im: c*Ey + s*Ox
    //   Bc += c*E - i s O -> Re: c*Ex + s*Oy, Im: c*Ey - s*Ox
    // Specials: ax=0 (t=1) -> both += f0; ax=12 (kxv=52) -> t12 / conj(t12).
    for (int idx = tid; idx < 396; idx += 256) {   // 33 hp * 12 kz
        int hp = idx / 12, kz = idx - (idx / 12) * 12;
        float2 f0  = fs[kz];
        float2 f12 = fs[12 * 12 + kz];
        float2 t12 = tw[(52 * hp) & 63];
        float2 A, Bc;
        A.x  = f0.x + f12.x * t12.x - f12.y * t12.y;
        A.y  = f0.y + f12.x * t12.y + f12.y * t12.x;
        Bc.x = f0.x + f12.x * t12.x + f12.y * t12.y;
        Bc.y = f0.y + f12.y * t12.x - f12.x * t12.y;
        for (int a = 1; a <= 11; ++a) {
            float2 fa = fs[a * 12 + kz];
            float2 fb = fs[(24 - a) * 12 + kz];
            float Ex = fa.x + fb.x, Ey = fa.y + fb.y;
            float Ox = fa.x - fb.x, Oy = fa.y - fb.y;
            float2 t = tw[(a * hp) & 63];
            A.x  += t.x * Ex - t.y * Oy;  A.y  += t.x * Ey + t.y * Ox;
            Bc.x += t.x * Ex + t.y * Oy;  Bc.y += t.x * Ey - t.y * Ox;
        }
        dst[hp * 288 + kz] = A;
        if (hp >= 1 && hp <= 31) dst[(64 - hp) * 288 + kz] = Bc;
    }
}

// ---------------------------------------------------------------------------
// Kernel 5: CFT branch — segment-0 Chebyshev (T0,T1,T2) + 3-freq rDFT over W.
// grid = B*C = 128 blocks, 256 threads = (q=w-group)*64 + d.
// cft[(b*64+d)*576 + c*18 + k*6 + f*2 + {re,im}]
// ---------------------------------------------------------------------------
__global__ __launch_bounds__(256) void k_cft(const float* __restrict__ x,
                                             float* __restrict__ cft) {
    __shared__ float2 tw[64];
    __shared__ float red[3 * 64 * 18];
    const int tid = threadIdx.x;
    const int blk = blockIdx.x;          // b*32 + c
    const int d = tid & 63, q = tid >> 6;
    fill_tw(tw, tid, 256);
    __syncthreads();
    float aR[3][3] = {{0.f}}, aI[3][3] = {{0.f}};
    const float* xb = x + (size_t)blk * 262144;
    for (int wi = 0; wi < 16; ++wi) {
        const int w = q * 16 + wi;
        float c0 = 0.f, c1 = 0.f, c2 = 0.f;
        #pragma unroll
        for (int s = 0; s < 8; ++s) {
            float xv = xb[(size_t)(s * 64 + w) * 64 + d];
            float t = (2.0f * (float)s - 7.0f) * (1.0f / 7.0f);
            c0 += xv;
            c1 += xv * t;
            c2 += xv * (2.0f * t * t - 1.0f);
        }
        c0 *= 0.125f; c1 *= 0.125f; c2 *= 0.125f;
        #pragma unroll
        for (int f = 0; f < 3; ++f) {
            float2 t = tw[(f * w) & 63];
            aR[0][f] += c0 * t.x; aI[0][f] -= c0 * t.y;
            aR[1][f] += c1 * t.x; aI[1][f] -= c1 * t.y;
            aR[2][f] += c2 * t.x; aI[2][f] -= c2 * t.y;
        }
    }
    if (q > 0) {
        float* dst = &red[((q - 1) * 64 + d) * 18];
        #pragma unroll
        for (int k = 0; k < 3; ++k)
            #pragma unroll
            for (int f = 0; f < 3; ++f) {
                dst[k * 6 + f * 2]     = aR[k][f];
                dst[k * 6 + f * 2 + 1] = aI[k][f];
            }
    }
    __syncthreads();
    if (q == 0) {
        #pragma unroll
        for (int qq = 0; qq < 3; ++qq) {
            const float* sr = &red[(qq * 64 + d) * 18];
            #pragma unroll
            for (int k = 0; k < 3; ++k)
                #pragma unroll
                for (int f = 0; f < 3; ++f) {
                    aR[k][f] += sr[k * 6 + f * 2];
                    aI[k][f] += sr[k * 6 + f * 2 + 1];
                }
        }
        const int b = blk >> 5, c = blk & 31;
        float* dst = cft + (size_t)(b * 64 + d) * 576 + c * 18;
        #pragma unroll
        for (int k = 0; k < 3; ++k)
            #pragma unroll
            for (int f = 0; f < 3; ++f) {
                dst[k * 6 + f * 2]     = aR[k][f];
                dst[k * 6 + f * 2 + 1] = aI[k][f];
            }
    }
}

// ---------------------------------------------------------------------------
// Kernel 6: MLP 576->128 (exact GeLU) ->32, pre-scaled by corr_scale.
// grid = B*D = 256 rows, 128 threads. corr[(b*32+o)*64 + d]
// ---------------------------------------------------------------------------
__global__ __launch_bounds__(128) void k_mlp(const float* __restrict__ cft,
                                             const float* __restrict__ w1,
                                             const float* __restrict__ b1,
                                             const float* __restrict__ w2,
                                             const float* __restrict__ b2,
                                             const float* __restrict__ cs,
                                             float* __restrict__ corr) {
    __shared__ float row[576];
    __shared__ float hbuf[128];
    const int n = blockIdx.x;            // b*64 + d
    const int tid = threadIdx.x;
    for (int i = tid; i < 576; i += 128) row[i] = cft[(size_t)n * 576 + i];
    __syncthreads();
    float acc = b1[tid];
    #pragma unroll 8
    for (int k = 0; k < 576; ++k) acc += row[k] * w1[k * 128 + tid];
    hbuf[tid] = 0.5f * acc * (1.0f + erff(acc * 0.70710678118654752f));
    __syncthreads();
    if (tid < 32) {
        float a2 = b2[tid];
        #pragma unroll 8
        for (int k = 0; k < 128; ++k) a2 += hbuf[k] * w2[k * 32 + tid];
        const int b = n >> 6, d = n & 63;
        corr[(b * 32 + tid) * 64 + d] = a2 * cs[0];
    }
}

// ---------------------------------------------------------------------------
// Kernel 7: fused inverse DFT along W (24->64) and D (12->64, c2r with c_kz),
// + correction add. grid = B*O*H = 8192, 256 threads.
// Stage A uses ky-mode conjugate pairing + E/O trick to share twiddle reads.
// ---------------------------------------------------------------------------
__global__ __launch_bounds__(256) void k_inv_yz(const float2* __restrict__ Y1,
                                                const float* __restrict__ corr,
                                                float* __restrict__ out) {
    __shared__ float2 y1[288];           // [a][kz]
    __shared__ float2 y2[64 * 12];       // [w][kz]
    __shared__ float2 tw[64];
    __shared__ float corrl[64];
    const int tid = threadIdx.x;
    const int blk = blockIdx.x;          // (b*32+o)*64 + h
    const int bo = blk >> 6;
    fill_tw(tw, tid, 256);
    for (int i = tid; i < 288; i += 256) y1[i] = Y1[(size_t)blk * 288 + i];
    if (tid < 64) corrl[tid] = corr[bo * 64 + tid];
    __syncthreads();
    // stage A: W inverse, e^{+i 2pi ky w / 64}; thread = (w, kz-triplet).
    // ky=0 (t=1), ky=52 (a=12) special; pairs a=1..11 with 24-a share t:
    // f1*(c+is) + f2*(c-is) = (c*E.x - s*O.y, c*E.y + s*O.x), E=f1+f2, O=f1-f2
    {
        const int w = tid >> 2, kz0 = (tid & 3) * 3;
        float2 a0 = make_float2(0.f, 0.f), a1 = a0, a2 = a0;
        {   // a = 0, ky = 0, t = (1,0)
            float2 f0 = y1[kz0], f1 = y1[kz0 + 1], f2 = y1[kz0 + 2];
            a0.x += f0.x; a0.y += f0.y;
            a1.x += f1.x; a1.y += f1.y;
            a2.x += f2.x; a2.y += f2.y;
        }
        {   // a = 12, ky = 52
            float2 t = tw[(52 * w) & 63];
            float2 f0 = y1[144 + kz0], f1 = y1[144 + kz0 + 1], f2 = y1[144 + kz0 + 2];
            a0.x += f0.x * t.x - f0.y * t.y; a0.y += f0.x * t.y + f0.y * t.x;
            a1.x += f1.x * t.x - f1.y * t.y; a1.y += f1.x * t.y + f1.y * t.x;
            a2.x += f2.x * t.x - f2.y * t.y; a2.y += f2.x * t.y + f2.y * t.x;
        }
        for (int a = 1; a <= 11; ++a) {
            float2 t = tw[(a * w) & 63];
            const float2* fa = &y1[a * 12 + kz0];
            const float2* fb = &y1[(24 - a) * 12 + kz0];
            float2 p0 = fa[0], p1 = fa[1], p2 = fa[2];
            float2 q0 = fb[0], q1 = fb[1], q2 = fb[2];
            float Ex, Ey, Ox, Oy;
            Ex = p0.x + q0.x; Ey = p0.y + q0.y; Ox = p0.x - q0.x; Oy = p0.y - q0.y;
            a0.x += t.x * Ex - t.y * Oy; a0.y += t.x * Ey + t.y * Ox;
            Ex = p1.x + q1.x; Ey = p1.y + q1.y; Ox = p1.x - q1.x; Oy = p1.y - q1.y;
            a1.x += t.x * Ex - t.y * Oy; a1.y += t.x * Ey + t.y * Ox;
            Ex = p2.x + q2.x; Ey = p2.y + q2.y; Ox = p2.x - q2.x; Oy = p2.y - q2.y;
            a2.x += t.x * Ex - t.y * Oy; a2.y += t.x * Ey + t.y * Ox;
        }
        y2[w * 12 + kz0]     = a0;
        y2[w * 12 + kz0 + 1] = a1;
        y2[w * 12 + kz0 + 2] = a2;
    }
    // per-thread fixed d: hoist the 12 D-twiddles (scaled) into registers
    float ctw[12], stw[12];
    const int d = tid & 63;
    #pragma unroll
    for (int kz = 0; kz < 12; ++kz) {
        float2 t = tw[(kz * d) & 63];
        float sc = (kz == 0 ? 1.0f : 2.0f) * (1.0f / 262144.0f);
        ctw[kz] = t.x * sc;
        stw[kz] = t.y * sc;
    }
    __syncthreads();
    const float cv = corrl[d];
    float* orow = out + (size_t)blk * 4096;
    const int wq = tid >> 6;
    for (int r = 0; r < 16; ++r) {
        int w = r * 4 + wq;
        float s = cv;
        #pragma unroll
        for (int kz = 0; kz < 12; ++kz) {
            float2 yv = y2[w * 12 + kz];
            s += yv.x * ctw[kz] - yv.y * stw[kz];  // Re(y * (c + i s)) scaled
        }
        orow[w * 64 + d] = s;
    }
}

// ---------------------------------------------------------------------------
extern "C" void kernel_launch(void* const* d_in, const int* in_sizes, int n_in,
                              void* d_out, int out_size, void* d_ws, size_t ws_size,
                              hipStream_t stream) {
    const float* x    = (const float*)d_in[0];
    const float* w1re = (const float*)d_in[1];
    const float* w1im = (const float*)d_in[2];
    const float* w2re = (const float*)d_in[3];
    const float* w2im = (const float*)d_in[4];
    const float* w3re = (const float*)d_in[5];
    const float* w3im = (const float*)d_in[6];
    const float* w4re = (const float*)d_in[7];
    const float* w4im = (const float*)d_in[8];
    const float* mw1  = (const float*)d_in[9];
    const float* mb1  = (const float*)d_in[10];
    const float* mw2  = (const float*)d_in[11];
    const float* mb2  = (const float*)d_in[12];
    const float* cs   = (const float*)d_in[13];
    float* out = (float*)d_out;

    char* ws = (char*)d_ws;
    float2* X2   = (float2*)(ws);                 // 18,874,368 B  (reused as Y1)
    float2* X3   = (float2*)(ws + 18874368);      //  7,077,888 B
    float2* F    = (float2*)(ws + 25952256);      //  7,077,888 B
    float*  cft  = (float*) (ws + 33030144);      //    589,824 B
    float*  corr = (float*) (ws + 33619968);      //     32,768 B
    float2* Y1   = X2;                            // X2 dead after k_fwd_x

    hipLaunchKernelGGL(k_fwd_zy, dim3(8192), dim3(256), 0, stream, x, X2);
    hipLaunchKernelGGL(k_fwd_x,  dim3(3072), dim3(256), 0, stream, X2, X3);
    hipLaunchKernelGGL(k_mix,    dim3(576),  dim3(384), 0, stream, X3, F,
                       w1re, w1im, w2re, w2im, w3re, w3im, w4re, w4im);
    hipLaunchKernelGGL(k_inv_x,  dim3(3072), dim3(256), 0, stream, F, Y1);
    hipLaunchKernelGGL(k_cft,    dim3(128),  dim3(256), 0, stream, x, cft);
    hipLaunchKernelGGL(k_mlp,    dim3(256),  dim3(128), 0, stream,
                       cft, mw1, mb1, mw2, mb2, cs, corr);
    hipLaunchKernelGGL(k_inv_yz, dim3(8192), dim3(256), 0, stream, Y1, corr, out);
}

// Round 3
// 476.315 us; speedup vs baseline: 1.0350x; 1.0350x over previous
//
#include <hip/hip_runtime.h>
#include <math.h>

// ---------------------------------------------------------------------------
// SpectralConv3d + Chebyshev-Fourier correction, fp32, pruned separable DFTs.
// B=4, C=O=32, H=W=D=64. Modes: kx in {0..11, 52..63} (24), ky same (24),
// kz in {0..11} (12).
// out = (1/64^3) * Re[ sum F[kx,ky,kz] * w^(kx h + ky w + kz d) * c_kz ]
//       + corr_scale * corr[b,o,d],  c_0 = 1, c_kz = 2 (kz>=1).
//
// R1: DFT symmetries (d<->64-d, conjugate output pairs, h<->64-h, E/O).
// R2: E/O pairing along the summation axes everywhere.
// R3 (this round, from rocprof: k_fwd_zy 121.8us, VALUBusy 47%, HBM 9% ->
//     LDS-issue bound):
//  - twiddle RECURRENCE t <- t*W^k (4 VALU) replaces every in-loop LDS
//    twiddle gather (was ~55% of LDS instructions in the DFT loops)
//  - float4 staging + float4 stage-B reads (12 b64 -> 6 b128) in k_inv_yz
// ---------------------------------------------------------------------------

#define CMUL_STEP(t, u) do { float _nx = (t).x*(u).x - (t).y*(u).y; \
    (t).y = (t).x*(u).y + (t).y*(u).x; (t).x = _nx; } while (0)

static __device__ __forceinline__ void fill_tw(float2* tw, int tid, int nthr) {
    // tw[m] = (cos(2 pi m / 64), sin(2 pi m / 64))
    for (int m = tid; m < 64; m += nthr) {
        float s, c;
        sincosf((float)m * 0.09817477042468103f, &s, &c);
        tw[m] = make_float2(c, s);
    }
}

// ---------------------------------------------------------------------------
// Kernel 1: fused forward DFT along D (64->12) and W (64->24).
// grid = B*C*H = 8192 blocks, 256 threads. X2[(bc*64+h)*288 + a*12 + kz]
// ---------------------------------------------------------------------------
__global__ __launch_bounds__(256) void k_fwd_zy(const float* __restrict__ x,
                                                float2* __restrict__ X2) {
    __shared__ float xt[64 * 68];        // [w][d], pad 68 to break conflicts
    __shared__ __align__(16) float2 z1[64 * 12];   // [w][kz]
    __shared__ float2 tw[64];
    const int tid = threadIdx.x;
    const int blk = blockIdx.x;          // (b*32+c)*64 + h
    fill_tw(tw, tid, 256);
    const float4* xrow4 = (const float4*)(x + (size_t)blk * 4096);
    for (int r = 0; r < 4; ++r) {
        int i4 = r * 256 + tid;          // 1024 float4 = 4096 floats
        int w = i4 >> 4, d4 = (i4 & 15) << 2;
        float4 v = xrow4[i4];
        *(float4*)&xt[w * 68 + d4] = v;
    }
    __syncthreads();
    // z-stage, real-input symmetry d <-> 64-d, twiddles by recurrence:
    // X[k] = x[0] + (-1)^k x[32]
    //      + sum_{d=1}^{31} (x[d]+x[64-d]) cos - i (x[d]-x[64-d]) sin
    {
        const int w = tid >> 2, kz0 = (tid & 3) * 3;
        const float* xr = &xt[w * 68];
        const float x0v = xr[0], x32v = xr[32];
        const float sg = (kz0 & 1) ? -x32v : x32v;   // (-1)^kz0 * x32
        float2 a0 = make_float2(x0v + sg, 0.f);      // k = kz0
        float2 a1 = make_float2(x0v - sg, 0.f);      // k = kz0+1
        float2 a2 = make_float2(x0v + sg, 0.f);      // k = kz0+2
        const float2 u0 = tw[kz0], u1 = tw[kz0 + 1], u2 = tw[kz0 + 2];
        float2 t0 = u0, t1 = u1, t2 = u2;            // t_k(d=1) = W^k
        for (int d = 1; d < 32; ++d) {
            float xa = xr[d], xb = xr[64 - d];
            float e = xa + xb, o = xa - xb;
            a0.x += e * t0.x; a0.y -= o * t0.y;
            a1.x += e * t1.x; a1.y -= o * t1.y;
            a2.x += e * t2.x; a2.y -= o * t2.y;
            CMUL_STEP(t0, u0); CMUL_STEP(t1, u1); CMUL_STEP(t2, u2);
        }
        z1[w * 12 + kz0]     = a0;
        z1[w * 12 + kz0 + 1] = a1;
        z1[w * 12 + kz0 + 2] = a2;
    }
    __syncthreads();
    // y-stage: output pairs (ky=ap, ky=64-ap) AND summation pairs w<->64-w.
    //   A  (ky=ap):    Re: c*Ex + s*Oy, Im: c*Ey - s*Ox
    //   Bc (ky=64-ap): Re: c*Ex - s*Oy, Im: c*Ey + s*Ox
    float2* xout = X2 + (size_t)blk * 288;
    if (tid < 156) {                     // 13 ap values * 12 kz
        const int ap = tid / 12, kz = tid - (tid / 12) * 12;
        const float2 zw0 = z1[kz];              // w = 0, t = (1,0)
        const float2 zw32 = z1[32 * 12 + kz];   // w = 32, t = (-1)^ap
        const float sg = (ap & 1) ? -1.f : 1.f;
        float2 A  = make_float2(zw0.x + sg * zw32.x, zw0.y + sg * zw32.y);
        float2 Bc = A;
        const float2 u = tw[ap];
        float2 t = u;                            // t(w=1) = W^ap
        for (int w = 1; w < 32; ++w) {
            float2 za = z1[w * 12 + kz];
            float2 zb = z1[(64 - w) * 12 + kz];
            float Ex = za.x + zb.x, Ey = za.y + zb.y;
            float Ox = za.x - zb.x, Oy = za.y - zb.y;
            A.x  += t.x * Ex + t.y * Oy;  A.y  += t.x * Ey - t.y * Ox;
            Bc.x += t.x * Ex - t.y * Oy;  Bc.y += t.x * Ey + t.y * Ox;
            CMUL_STEP(t, u);
        }
        if (ap <= 11) xout[ap * 12 + kz] = A;
        if (ap >= 1)  xout[(24 - ap) * 12 + kz] = Bc;
    }
}

// ---------------------------------------------------------------------------
// Kernel 2: forward DFT along H (64->24), conjugate-mode + summation pairing.
// grid = B*C*24 = 3072, 256 threads. X3[bc*6912 + ax*288 + ay*12 + kz]
// ---------------------------------------------------------------------------
__global__ __launch_bounds__(256) void k_fwd_x(const float2* __restrict__ X2,
                                               float2* __restrict__ X3) {
    __shared__ __align__(16) float2 s2[64 * 12];   // [h][kz]
    __shared__ float2 tw[64];
    const int tid = threadIdx.x;
    const int blk = blockIdx.x;
    const int ay = blk % 24, bc = blk / 24;
    fill_tw(tw, tid, 256);
    const float2* src = X2 + (size_t)bc * (64 * 288) + ay * 12;
    for (int i4 = tid; i4 < 384; i4 += 256) {      // 64 rows * 6 float4
        int hh = i4 / 6, c4 = i4 - hh * 6;
        ((float4*)&s2[hh * 12])[c4] = ((const float4*)(src + (size_t)hh * 288))[c4];
    }
    __syncthreads();
    float2* dst = X3 + (size_t)bc * 6912 + ay * 12;
    if (tid < 156) {                     // 13 ap values * 12 kz
        const int ap = tid / 12, kz = tid - (tid / 12) * 12;
        const float2 zw0 = s2[kz];              // hh = 0
        const float2 zw32 = s2[32 * 12 + kz];   // hh = 32
        const float sg = (ap & 1) ? -1.f : 1.f;
        float2 A  = make_float2(zw0.x + sg * zw32.x, zw0.y + sg * zw32.y);
        float2 Bc = A;
        const float2 u = tw[ap];
        float2 t = u;
        for (int hh = 1; hh < 32; ++hh) {
            float2 za = s2[hh * 12 + kz];
            float2 zb = s2[(64 - hh) * 12 + kz];
            float Ex = za.x + zb.x, Ey = za.y + zb.y;
            float Ox = za.x - zb.x, Oy = za.y - zb.y;
            A.x  += t.x * Ex + t.y * Oy;  A.y  += t.x * Ey - t.y * Ox;
            Bc.x += t.x * Ex - t.y * Oy;  Bc.y += t.x * Ey + t.y * Ox;
            CMUL_STEP(t, u);
        }
        if (ap <= 11) dst[ap * 288 + kz] = A;
        if (ap >= 1)  dst[(24 - ap) * 288 + kz] = Bc;
    }
}

// ---------------------------------------------------------------------------
// Kernel 3: mode mixing F[b,o,m] = sum_i X3[b,i,m] * (wre + i wim)[i,o,m].
// grid = 24*24 = 576 blocks (one (ax,ay)), 384 threads = (o,kz).
// Weights streamed from global exactly once in total.
// ---------------------------------------------------------------------------
__global__ __launch_bounds__(384) void k_mix(const float2* __restrict__ X3,
                                             float2* __restrict__ F,
        const float* __restrict__ w1re, const float* __restrict__ w1im,
        const float* __restrict__ w2re, const float* __restrict__ w2im,
        const float* __restrict__ w3re, const float* __restrict__ w3im,
        const float* __restrict__ w4re, const float* __restrict__ w4im) {
    __shared__ float2 xs[128 * 12];      // [b*32+i][kz]
    const int tid = threadIdx.x;
    const int blk = blockIdx.x;
    const int ax = blk / 24, ay = blk % 24;
    const int cx = ax >= 12 ? 1 : 0, cy = ay >= 12 ? 1 : 0;
    const int m1 = ax - cx * 12, m2 = ay - cy * 12;
    const int sel = cx + cy * 2;         // 0:w1 (lo,lo) 1:w2 (hi,lo) 2:w3 (lo,hi) 3:w4
    const float* wre = sel == 0 ? w1re : sel == 1 ? w2re : sel == 2 ? w3re : w4re;
    const float* wim = sel == 0 ? w1im : sel == 1 ? w2im : sel == 2 ? w3im : w4im;
    const size_t moff = (size_t)ax * 288 + (size_t)ay * 12;
    for (int i = tid; i < 1536; i += 384) {
        int bi = i / 12, kz = i - bi * 12;
        xs[i] = X3[(size_t)bi * 6912 + moff + kz];
    }
    __syncthreads();
    const int o = tid / 12, kz = tid - (tid / 12) * 12;
    const int wbase = o * 1728 + m1 * 144 + m2 * 12 + kz;
    float2 A0 = make_float2(0.f, 0.f), A1 = A0, A2 = A0, A3 = A0;
    for (int i = 0; i < 32; ++i) {
        float wr = wre[i * 55296 + wbase];
        float wi = wim[i * 55296 + wbase];
        float2 x0 = xs[i * 12 + kz];
        float2 x1 = xs[(32 + i) * 12 + kz];
        float2 x2 = xs[(64 + i) * 12 + kz];
        float2 x3 = xs[(96 + i) * 12 + kz];
        A0.x += x0.x * wr - x0.y * wi; A0.y += x0.x * wi + x0.y * wr;
        A1.x += x1.x * wr - x1.y * wi; A1.y += x1.x * wi + x1.y * wr;
        A2.x += x2.x * wr - x2.y * wi; A2.y += x2.x * wi + x2.y * wr;
        A3.x += x3.x * wr - x3.y * wi; A3.y += x3.x * wi + x3.y * wr;
    }
    F[(size_t)(0 * 32 + o) * 6912 + moff + kz] = A0;
    F[(size_t)(1 * 32 + o) * 6912 + moff + kz] = A1;
    F[(size_t)(2 * 32 + o) * 6912 + moff + kz] = A2;
    F[(size_t)(3 * 32 + o) * 6912 + moff + kz] = A3;
}

// ---------------------------------------------------------------------------
// Kernel 4: inverse DFT along H (24->64): output pairing h <-> 64-h composed
// with input-mode pairing ax <-> 24-ax; twiddles by recurrence (t <- t*W^hp).
// grid = B*O*24 = 3072, 256 threads. Y1[(bo*64+h)*288 + ay*12 + kz]
// ---------------------------------------------------------------------------
__global__ __launch_bounds__(256) void k_inv_x(const float2* __restrict__ F,
                                               float2* __restrict__ Y1) {
    __shared__ __align__(16) float2 fs[24 * 12];
    __shared__ float2 tw[64];
    const int tid = threadIdx.x;
    const int blk = blockIdx.x;
    const int ay = blk % 24, bo = blk / 24;
    fill_tw(tw, tid, 256);
    const float2* src = F + (size_t)bo * 6912 + ay * 12;
    for (int i4 = tid; i4 < 144; i4 += 256) {      // 24 rows * 6 float4
        int ax = i4 / 6, c4 = i4 - ax * 6;
        ((float4*)&fs[ax * 12])[c4] = ((const float4*)(src + (size_t)ax * 288))[c4];
    }
    __syncthreads();
    float2* dst = Y1 + (size_t)bo * (64 * 288) + ay * 12;
    // hp in 0..32: A -> h=hp; Bc -> h=64-hp (hp in 1..31).
    //   A  += c*E - s*Oy | c*Ey + s*Ox ;  Bc += c*E + s*Oy | c*Ey - s*Ox
    for (int idx = tid; idx < 396; idx += 256) {   // 33 hp * 12 kz
        int hp = idx / 12, kz = idx - (idx / 12) * 12;
        float2 f0  = fs[kz];
        float2 f12 = fs[12 * 12 + kz];
        float2 t12 = tw[(52 * hp) & 63];
        float2 A, Bc;
        A.x  = f0.x + f12.x * t12.x - f12.y * t12.y;
        A.y  = f0.y + f12.x * t12.y + f12.y * t12.x;
        Bc.x = f0.x + f12.x * t12.x + f12.y * t12.y;
        Bc.y = f0.y + f12.y * t12.x - f12.x * t12.y;
        const float2 u = tw[hp];         // hp <= 32 < 64
        float2 t = u;                    // t(a=1) = W^hp
        for (int a = 1; a <= 11; ++a) {
            float2 fa = fs[a * 12 + kz];
            float2 fb = fs[(24 - a) * 12 + kz];
            float Ex = fa.x + fb.x, Ey = fa.y + fb.y;
            float Ox = fa.x - fb.x, Oy = fa.y - fb.y;
            A.x  += t.x * Ex - t.y * Oy;  A.y  += t.x * Ey + t.y * Ox;
            Bc.x += t.x * Ex + t.y * Oy;  Bc.y += t.x * Ey - t.y * Ox;
            CMUL_STEP(t, u);
        }
        dst[hp * 288 + kz] = A;
        if (hp >= 1 && hp <= 31) dst[(64 - hp) * 288 + kz] = Bc;
    }
}

// ---------------------------------------------------------------------------
// Kernel 5: CFT branch — segment-0 Chebyshev (T0,T1,T2) + 3-freq rDFT over W.
// grid = B*C = 128 blocks, 256 threads = (q=w-group)*64 + d.
// cft[(b*64+d)*576 + c*18 + k*6 + f*2 + {re,im}]
// ---------------------------------------------------------------------------
__global__ __launch_bounds__(256) void k_cft(const float* __restrict__ x,
                                             float* __restrict__ cft) {
    __shared__ float2 tw[64];
    __shared__ float red[3 * 64 * 18];
    const int tid = threadIdx.x;
    const int blk = blockIdx.x;          // b*32 + c
    const int d = tid & 63, q = tid >> 6;
    fill_tw(tw, tid, 256);
    __syncthreads();
    float aR[3][3] = {{0.f}}, aI[3][3] = {{0.f}};
    const float* xb = x + (size_t)blk * 262144;
    for (int wi = 0; wi < 16; ++wi) {
        const int w = q * 16 + wi;
        float c0 = 0.f, c1 = 0.f, c2 = 0.f;
        #pragma unroll
        for (int s = 0; s < 8; ++s) {
            float xv = xb[(size_t)(s * 64 + w) * 64 + d];
            float t = (2.0f * (float)s - 7.0f) * (1.0f / 7.0f);
            c0 += xv;
            c1 += xv * t;
            c2 += xv * (2.0f * t * t - 1.0f);
        }
        c0 *= 0.125f; c1 *= 0.125f; c2 *= 0.125f;
        #pragma unroll
        for (int f = 0; f < 3; ++f) {
            float2 t = tw[(f * w) & 63];
            aR[0][f] += c0 * t.x; aI[0][f] -= c0 * t.y;
            aR[1][f] += c1 * t.x; aI[1][f] -= c1 * t.y;
            aR[2][f] += c2 * t.x; aI[2][f] -= c2 * t.y;
        }
    }
    if (q > 0) {
        float* dst = &red[((q - 1) * 64 + d) * 18];
        #pragma unroll
        for (int k = 0; k < 3; ++k)
            #pragma unroll
            for (int f = 0; f < 3; ++f) {
                dst[k * 6 + f * 2]     = aR[k][f];
                dst[k * 6 + f * 2 + 1] = aI[k][f];
            }
    }
    __syncthreads();
    if (q == 0) {
        #pragma unroll
        for (int qq = 0; qq < 3; ++qq) {
            const float* sr = &red[(qq * 64 + d) * 18];
            #pragma unroll
            for (int k = 0; k < 3; ++k)
                #pragma unroll
                for (int f = 0; f < 3; ++f) {
                    aR[k][f] += sr[k * 6 + f * 2];
                    aI[k][f] += sr[k * 6 + f * 2 + 1];
                }
        }
        const int b = blk >> 5, c = blk & 31;
        float* dst = cft + (size_t)(b * 64 + d) * 576 + c * 18;
        #pragma unroll
        for (int k = 0; k < 3; ++k)
            #pragma unroll
            for (int f = 0; f < 3; ++f) {
                dst[k * 6 + f * 2]     = aR[k][f];
                dst[k * 6 + f * 2 + 1] = aI[k][f];
            }
    }
}

// ---------------------------------------------------------------------------
// Kernel 6: MLP 576->128 (exact GeLU) ->32, pre-scaled by corr_scale.
// grid = B*D = 256 rows, 128 threads. corr[(b*32+o)*64 + d]
// ---------------------------------------------------------------------------
__global__ __launch_bounds__(128) void k_mlp(const float* __restrict__ cft,
                                             const float* __restrict__ w1,
                                             const float* __restrict__ b1,
                                             const float* __restrict__ w2,
                                             const float* __restrict__ b2,
                                             const float* __restrict__ cs,
                                             float* __restrict__ corr) {
    __shared__ float row[576];
    __shared__ float hbuf[128];
    const int n = blockIdx.x;            // b*64 + d
    const int tid = threadIdx.x;
    for (int i = tid; i < 576; i += 128) row[i] = cft[(size_t)n * 576 + i];
    __syncthreads();
    float acc = b1[tid];
    #pragma unroll 8
    for (int k = 0; k < 576; ++k) acc += row[k] * w1[k * 128 + tid];
    hbuf[tid] = 0.5f * acc * (1.0f + erff(acc * 0.70710678118654752f));
    __syncthreads();
    if (tid < 32) {
        float a2 = b2[tid];
        #pragma unroll 8
        for (int k = 0; k < 128; ++k) a2 += hbuf[k] * w2[k * 32 + tid];
        const int b = n >> 6, d = n & 63;
        corr[(b * 32 + tid) * 64 + d] = a2 * cs[0];
    }
}

// ---------------------------------------------------------------------------
// Kernel 7: fused inverse DFT along W (24->64) and D (12->64, c2r with c_kz),
// + correction add. grid = B*O*H = 8192, 256 threads.
// Stage A: mode-pair E/O + twiddle recurrence. Stage B: float4 y2 reads.
// ---------------------------------------------------------------------------
__global__ __launch_bounds__(256) void k_inv_yz(const float2* __restrict__ Y1,
                                                const float* __restrict__ corr,
                                                float* __restrict__ out) {
    __shared__ __align__(16) float2 y1[288];       // [a][kz]
    __shared__ __align__(16) float2 y2[64 * 12];   // [w][kz]
    __shared__ float2 tw[64];
    __shared__ float corrl[64];
    const int tid = threadIdx.x;
    const int blk = blockIdx.x;          // (b*32+o)*64 + h
    const int bo = blk >> 6;
    fill_tw(tw, tid, 256);
    {
        const float4* src4 = (const float4*)(Y1 + (size_t)blk * 288);
        for (int i4 = tid; i4 < 144; i4 += 256) ((float4*)y1)[i4] = src4[i4];
    }
    if (tid < 64) corrl[tid] = corr[bo * 64 + tid];
    __syncthreads();
    // stage A: W inverse, e^{+i 2pi ky w / 64}; thread = (w, kz-triplet).
    // ky=0 (t=1), ky=52 (a=12) special; pairs a=1..11 with 24-a share t:
    // f1*(c+is) + f2*(c-is) = (c*E.x - s*O.y, c*E.y + s*O.x), E=f1+f2, O=f1-f2
    {
        const int w = tid >> 2, kz0 = (tid & 3) * 3;
        float2 a0 = make_float2(0.f, 0.f), a1 = a0, a2 = a0;
        {   // a = 0, ky = 0, t = (1,0)
            float2 f0 = y1[kz0], f1 = y1[kz0 + 1], f2 = y1[kz0 + 2];
            a0.x += f0.x; a0.y += f0.y;
            a1.x += f1.x; a1.y += f1.y;
            a2.x += f2.x; a2.y += f2.y;
        }
        {   // a = 12, ky = 52
            float2 t = tw[(52 * w) & 63];
            float2 f0 = y1[144 + kz0], f1 = y1[144 + kz0 + 1], f2 = y1[144 + kz0 + 2];
            a0.x += f0.x * t.x - f0.y * t.y; a0.y += f0.x * t.y + f0.y * t.x;
            a1.x += f1.x * t.x - f1.y * t.y; a1.y += f1.x * t.y + f1.y * t.x;
            a2.x += f2.x * t.x - f2.y * t.y; a2.y += f2.x * t.y + f2.y * t.x;
        }
        const float2 u = tw[w];
        float2 t = u;                    // t(a=1) = W^w
        for (int a = 1; a <= 11; ++a) {
            const float2* fa = &y1[a * 12 + kz0];
            const float2* fb = &y1[(24 - a) * 12 + kz0];
            float2 p0 = fa[0], p1 = fa[1], p2 = fa[2];
            float2 q0 = fb[0], q1 = fb[1], q2 = fb[2];
            float Ex, Ey, Ox, Oy;
            Ex = p0.x + q0.x; Ey = p0.y + q0.y; Ox = p0.x - q0.x; Oy = p0.y - q0.y;
            a0.x += t.x * Ex - t.y * Oy; a0.y += t.x * Ey + t.y * Ox;
            Ex = p1.x + q1.x; Ey = p1.y + q1.y; Ox = p1.x - q1.x; Oy = p1.y - q1.y;
            a1.x += t.x * Ex - t.y * Oy; a1.y += t.x * Ey + t.y * Ox;
            Ex = p2.x + q2.x; Ey = p2.y + q2.y; Ox = p2.x - q2.x; Oy = p2.y - q2.y;
            a2.x += t.x * Ex - t.y * Oy; a2.y += t.x * Ey + t.y * Ox;
            CMUL_STEP(t, u);
        }
        y2[w * 12 + kz0]     = a0;
        y2[w * 12 + kz0 + 1] = a1;
        y2[w * 12 + kz0 + 2] = a2;
    }
    // per-thread fixed d: hoist the 12 D-twiddles (scaled) into registers
    float ctw[12], stw[12];
    const int d = tid & 63;
    #pragma unroll
    for (int kz = 0; kz < 12; ++kz) {
        float2 t = tw[(kz * d) & 63];
        float sc = (kz == 0 ? 1.0f : 2.0f) * (1.0f / 262144.0f);
        ctw[kz] = t.x * sc;
        stw[kz] = t.y * sc;
    }
    __syncthreads();
    const float cv = corrl[d];
    float* orow = out + (size_t)blk * 4096;
    const int wq = tid >> 6;
    for (int r = 0; r < 16; ++r) {
        int w = r * 4 + wq;
        const float4* yv = (const float4*)&y2[w * 12];   // 12 float2 = 6 float4
        float4 p0 = yv[0], p1 = yv[1], p2 = yv[2];
        float4 p3 = yv[3], p4 = yv[4], p5 = yv[5];
        float s = cv;
        s += p0.x * ctw[0]  - p0.y * stw[0];
        s += p0.z * ctw[1]  - p0.w * stw[1];
        s += p1.x * ctw[2]  - p1.y * stw[2];
        s += p1.z * ctw[3]  - p1.w * stw[3];
        s += p2.x * ctw[4]  - p2.y * stw[4];
        s += p2.z * ctw[5]  - p2.w * stw[5];
        s += p3.x * ctw[6]  - p3.y * stw[6];
        s += p3.z * ctw[7]  - p3.w * stw[7];
        s += p4.x * ctw[8]  - p4.y * stw[8];
        s += p4.z * ctw[9]  - p4.w * stw[9];
        s += p5.x * ctw[10] - p5.y * stw[10];
        s += p5.z * ctw[11] - p5.w * stw[11];
        orow[w * 64 + d] = s;
    }
}

// ---------------------------------------------------------------------------
extern "C" void kernel_launch(void* const* d_in, const int* in_sizes, int n_in,
                              void* d_out, int out_size, void* d_ws, size_t ws_size,
                              hipStream_t stream) {
    const float* x    = (const float*)d_in[0];
    const float* w1re = (const float*)d_in[1];
    const float* w1im = (const float*)d_in[2];
    const float* w2re = (const float*)d_in[3];
    const float* w2im = (const float*)d_in[4];
    const float* w3re = (const float*)d_in[5];
    const float* w3im = (const float*)d_in[6];
    const float* w4re = (const float*)d_in[7];
    const float* w4im = (const float*)d_in[8];
    const float* mw1  = (const float*)d_in[9];
    const float* mb1  = (const float*)d_in[10];
    const float* mw2  = (const float*)d_in[11];
    const float* mb2  = (const float*)d_in[12];
    const float* cs   = (const float*)d_in[13];
    float* out = (float*)d_out;

    char* ws = (char*)d_ws;
    float2* X2   = (float2*)(ws);                 // 18,874,368 B  (reused as Y1)
    float2* X3   = (float2*)(ws + 18874368);      //  7,077,888 B
    float2* F    = (float2*)(ws + 25952256);      //  7,077,888 B
    float*  cft  = (float*) (ws + 33030144);      //    589,824 B
    float*  corr = (float*) (ws + 33619968);      //     32,768 B
    float2* Y1   = X2;                            // X2 dead after k_fwd_x

    hipLaunchKernelGGL(k_fwd_zy, dim3(8192), dim3(256), 0, stream, x, X2);
    hipLaunchKernelGGL(k_fwd_x,  dim3(3072), dim3(256), 0, stream, X2, X3);
    hipLaunchKernelGGL(k_mix,    dim3(576),  dim3(384), 0, stream, X3, F,
                       w1re, w1im, w2re, w2im, w3re, w3im, w4re, w4im);
    hipLaunchKernelGGL(k_inv_x,  dim3(3072), dim3(256), 0, stream, F, Y1);
    hipLaunchKernelGGL(k_cft,    dim3(128),  dim3(256), 0, stream, x, cft);
    hipLaunchKernelGGL(k_mlp,    dim3(256),  dim3(128), 0, stream,
                       cft, mw1, mb1, mw2, mb2, cs, corr);
    hipLaunchKernelGGL(k_inv_yz, dim3(8192), dim3(256), 0, stream, Y1, corr, out);
}

// Round 4
// 468.708 us; speedup vs baseline: 1.0518x; 1.0162x over previous
//
#include <hip/hip_runtime.h>
#include <math.h>

// ---------------------------------------------------------------------------
// SpectralConv3d + Chebyshev-Fourier correction, fp32, pruned separable DFTs.
// B=4, C=O=32, H=W=D=64. Modes: kx in {0..11, 52..63} (24), ky same (24),
// kz in {0..11} (12).
// out = (1/64^3) * Re[ sum F[kx,ky,kz] * w^(kx h + ky w + kz d) * c_kz ]
//       + corr_scale * corr[b,o,d],  c_0 = 1, c_kz = 2 (kz>=1).
//
// R1: DFT symmetries (d<->64-d, conjugate output pairs, h<->64-h, E/O).
// R2: E/O pairing along the summation axes everywhere.
// R3: twiddle recurrence replaced LDS gathers (conflicts 237K->0, but moved
//     cost to VALU: 12 CMUL-VALU/iter; k_fwd_zy 104us, VALU-bound).
// R4 (this round): k_fwd_zy z-stage with COMPILE-TIME LITERAL twiddles:
//     wave-uniform kz-triplet (template<KZ0>, wave q -> kz0=3q), lane = w,
//     full unroll d=1..31 -> v_fmac with literal constants, no CMUL, no
//     twiddle memory. LDS re-layout: xt[d][65] (conflict-free lane reads,
//     immediate-offset addressing), z1k[12][66] (broadcast y-reads).
// ---------------------------------------------------------------------------

#define CMUL_STEP(t, u) do { float _nx = (t).x*(u).x - (t).y*(u).y; \
    (t).y = (t).x*(u).y + (t).y*(u).x; (t).x = _nx; } while (0)

// cos(2*pi*m/64), m = 0..63 (sin(m) = cos((m+48)&63))
constexpr float TW_C[64] = {
     1.000000000000000f,  0.995184726672197f,  0.980785280403230f,  0.956940335732209f,
     0.923879532511287f,  0.881921264348355f,  0.831469612302545f,  0.773010453362737f,
     0.707106781186548f,  0.634393284163645f,  0.555570233019602f,  0.471396736825998f,
     0.382683432365090f,  0.290284677254462f,  0.195090322016128f,  0.098017140329561f,
     0.000000000000000f, -0.098017140329561f, -0.195090322016128f, -0.290284677254462f,
    -0.382683432365090f, -0.471396736825998f, -0.555570233019602f, -0.634393284163645f,
    -0.707106781186548f, -0.773010453362737f, -0.831469612302545f, -0.881921264348355f,
    -0.923879532511287f, -0.956940335732209f, -0.980785280403230f, -0.995184726672197f,
    -1.000000000000000f, -0.995184726672197f, -0.980785280403230f, -0.956940335732209f,
    -0.923879532511287f, -0.881921264348355f, -0.831469612302545f, -0.773010453362737f,
    -0.707106781186548f, -0.634393284163645f, -0.555570233019602f, -0.471396736825998f,
    -0.382683432365090f, -0.290284677254462f, -0.195090322016128f, -0.098017140329561f,
     0.000000000000000f,  0.098017140329561f,  0.195090322016128f,  0.290284677254462f,
     0.382683432365090f,  0.471396736825998f,  0.555570233019602f,  0.634393284163645f,
     0.707106781186548f,  0.773010453362737f,  0.831469612302545f,  0.881921264348355f,
     0.923879532511287f,  0.956940335732209f,  0.980785280403230f,  0.995184726672197f
};
constexpr float twc(int m) { return TW_C[m & 63]; }
constexpr float tws(int m) { return TW_C[(m + 48) & 63]; }

static __device__ __forceinline__ void fill_tw(float2* tw, int tid, int nthr) {
    // tw[m] = (cos(2 pi m / 64), sin(2 pi m / 64))
    for (int m = tid; m < 64; m += nthr) {
        float s, c;
        sincosf((float)m * 0.09817477042468103f, &s, &c);
        tw[m] = make_float2(c, s);
    }
}

// ---------------------------------------------------------------------------
// Kernel 1: fused forward DFT along D (64->12) and W (64->24).
// grid = B*C*H = 8192 blocks, 256 threads. X2[(bc*64+h)*288 + a*12 + kz]
// z-stage: wave q owns kz {3q,3q+1,3q+2}, lane = w. Literal twiddles.
// ---------------------------------------------------------------------------
template<int KZ0>
static __device__ __forceinline__ void zstage_wave(const float* __restrict__ xt,
                                                   float2* __restrict__ z1k,
                                                   int w) {
    const float x0v  = xt[w];             // d = 0
    const float x32v = xt[32 * 65 + w];   // d = 32
    float a0x = x0v + (((KZ0    ) & 1) ? -x32v : x32v), a0y = 0.f;
    float a1x = x0v + (((KZ0 + 1) & 1) ? -x32v : x32v), a1y = 0.f;
    float a2x = x0v + (((KZ0 + 2) & 1) ? -x32v : x32v), a2y = 0.f;
    #pragma unroll
    for (int d = 1; d < 32; ++d) {
        const float xa = xt[d * 65 + w];
        const float xb = xt[(64 - d) * 65 + w];
        const float e = xa + xb, o = xa - xb;
        a0x += e * twc((KZ0    ) * d);  a0y -= o * tws((KZ0    ) * d);
        a1x += e * twc((KZ0 + 1) * d);  a1y -= o * tws((KZ0 + 1) * d);
        a2x += e * twc((KZ0 + 2) * d);  a2y -= o * tws((KZ0 + 2) * d);
    }
    z1k[(KZ0    ) * 66 + w] = make_float2(a0x, a0y);
    z1k[(KZ0 + 1) * 66 + w] = make_float2(a1x, a1y);
    z1k[(KZ0 + 2) * 66 + w] = make_float2(a2x, a2y);
}

__global__ __launch_bounds__(256) void k_fwd_zy(const float* __restrict__ x,
                                                float2* __restrict__ X2) {
    __shared__ float xt[64 * 65];                  // [d][w], odd stride
    __shared__ __align__(16) float2 z1k[12 * 66];  // [kz][w], pad 66
    const int tid = threadIdx.x;
    const int blk = blockIdx.x;          // (b*32+c)*64 + h
    // stage x row (transposed to [d][w]): thread i4 covers (w, d4..d4+3)
    const float4* xrow4 = (const float4*)(x + (size_t)blk * 4096);
    for (int r = 0; r < 4; ++r) {
        int i4 = r * 256 + tid;          // 1024 float4 = 4096 floats
        int w = i4 >> 4, d4 = (i4 & 15) << 2;
        float4 v = xrow4[i4];
        xt[(d4 + 0) * 65 + w] = v.x;
        xt[(d4 + 1) * 65 + w] = v.y;
        xt[(d4 + 2) * 65 + w] = v.z;
        xt[(d4 + 3) * 65 + w] = v.w;
    }
    __syncthreads();
    {
        const int q = tid >> 6, w = tid & 63;
        switch (q) {
            case 0: zstage_wave<0>(xt, z1k, w); break;
            case 1: zstage_wave<3>(xt, z1k, w); break;
            case 2: zstage_wave<6>(xt, z1k, w); break;
            default: zstage_wave<9>(xt, z1k, w); break;
        }
    }
    __syncthreads();
    // y-stage: output pairs (ky=ap, ky=64-ap) AND summation pairs w<->64-w.
    //   A  (ky=ap):    Re: c*Ex + s*Oy, Im: c*Ey - s*Ox
    //   Bc (ky=64-ap): Re: c*Ex - s*Oy, Im: c*Ey + s*Ox
    float2* xout = X2 + (size_t)blk * 288;
    if (tid < 156) {                     // 13 ap values * 12 kz
        const int ap = tid / 12, kz = tid - (tid / 12) * 12;
        const float2* zr = &z1k[kz * 66];
        const float2 zw0 = zr[0];               // w = 0, t = (1,0)
        const float2 zw32 = zr[32];             // w = 32, t = (-1)^ap
        const float sg = (ap & 1) ? -1.f : 1.f;
        float2 A  = make_float2(zw0.x + sg * zw32.x, zw0.y + sg * zw32.y);
        float2 Bc = A;
        float s_, c_;
        sincosf((float)ap * 0.09817477042468103f, &s_, &c_);
        const float2 u = make_float2(c_, s_);
        float2 t = u;                            // t(w=1) = W^ap
        for (int w = 1; w < 32; ++w) {
            float2 za = zr[w];
            float2 zb = zr[64 - w];
            float Ex = za.x + zb.x, Ey = za.y + zb.y;
            float Ox = za.x - zb.x, Oy = za.y - zb.y;
            A.x  += t.x * Ex + t.y * Oy;  A.y  += t.x * Ey - t.y * Ox;
            Bc.x += t.x * Ex - t.y * Oy;  Bc.y += t.x * Ey + t.y * Ox;
            CMUL_STEP(t, u);
        }
        if (ap <= 11) xout[ap * 12 + kz] = A;
        if (ap >= 1)  xout[(24 - ap) * 12 + kz] = Bc;
    }
}

// ---------------------------------------------------------------------------
// Kernel 2: forward DFT along H (64->24), conjugate-mode + summation pairing.
// grid = B*C*24 = 3072, 256 threads. X3[bc*6912 + ax*288 + ay*12 + kz]
// ---------------------------------------------------------------------------
__global__ __launch_bounds__(256) void k_fwd_x(const float2* __restrict__ X2,
                                               float2* __restrict__ X3) {
    __shared__ __align__(16) float2 s2[64 * 12];   // [h][kz]
    __shared__ float2 tw[64];
    const int tid = threadIdx.x;
    const int blk = blockIdx.x;
    const int ay = blk % 24, bc = blk / 24;
    fill_tw(tw, tid, 256);
    const float2* src = X2 + (size_t)bc * (64 * 288) + ay * 12;
    for (int i4 = tid; i4 < 384; i4 += 256) {      // 64 rows * 6 float4
        int hh = i4 / 6, c4 = i4 - hh * 6;
        ((float4*)&s2[hh * 12])[c4] = ((const float4*)(src + (size_t)hh * 288))[c4];
    }
    __syncthreads();
    float2* dst = X3 + (size_t)bc * 6912 + ay * 12;
    if (tid < 156) {                     // 13 ap values * 12 kz
        const int ap = tid / 12, kz = tid - (tid / 12) * 12;
        const float2 zw0 = s2[kz];              // hh = 0
        const float2 zw32 = s2[32 * 12 + kz];   // hh = 32
        const float sg = (ap & 1) ? -1.f : 1.f;
        float2 A  = make_float2(zw0.x + sg * zw32.x, zw0.y + sg * zw32.y);
        float2 Bc = A;
        const float2 u = tw[ap];
        float2 t = u;
        for (int hh = 1; hh < 32; ++hh) {
            float2 za = s2[hh * 12 + kz];
            float2 zb = s2[(64 - hh) * 12 + kz];
            float Ex = za.x + zb.x, Ey = za.y + zb.y;
            float Ox = za.x - zb.x, Oy = za.y - zb.y;
            A.x  += t.x * Ex + t.y * Oy;  A.y  += t.x * Ey - t.y * Ox;
            Bc.x += t.x * Ex - t.y * Oy;  Bc.y += t.x * Ey + t.y * Ox;
            CMUL_STEP(t, u);
        }
        if (ap <= 11) dst[ap * 288 + kz] = A;
        if (ap >= 1)  dst[(24 - ap) * 288 + kz] = Bc;
    }
}

// ---------------------------------------------------------------------------
// Kernel 3: mode mixing F[b,o,m] = sum_i X3[b,i,m] * (wre + i wim)[i,o,m].
// grid = 24*24 = 576 blocks (one (ax,ay)), 384 threads = (o,kz).
// Weights streamed from global exactly once in total.
// ---------------------------------------------------------------------------
__global__ __launch_bounds__(384) void k_mix(const float2* __restrict__ X3,
                                             float2* __restrict__ F,
        const float* __restrict__ w1re, const float* __restrict__ w1im,
        const float* __restrict__ w2re, const float* __restrict__ w2im,
        const float* __restrict__ w3re, const float* __restrict__ w3im,
        const float* __restrict__ w4re, const float* __restrict__ w4im) {
    __shared__ float2 xs[128 * 12];      // [b*32+i][kz]
    const int tid = threadIdx.x;
    const int blk = blockIdx.x;
    const int ax = blk / 24, ay = blk % 24;
    const int cx = ax >= 12 ? 1 : 0, cy = ay >= 12 ? 1 : 0;
    const int m1 = ax - cx * 12, m2 = ay - cy * 12;
    const int sel = cx + cy * 2;         // 0:w1 (lo,lo) 1:w2 (hi,lo) 2:w3 (lo,hi) 3:w4
    const float* wre = sel == 0 ? w1re : sel == 1 ? w2re : sel == 2 ? w3re : w4re;
    const float* wim = sel == 0 ? w1im : sel == 1 ? w2im : sel == 2 ? w3im : w4im;
    const size_t moff = (size_t)ax * 288 + (size_t)ay * 12;
    for (int i = tid; i < 1536; i += 384) {
        int bi = i / 12, kz = i - bi * 12;
        xs[i] = X3[(size_t)bi * 6912 + moff + kz];
    }
    __syncthreads();
    const int o = tid / 12, kz = tid - (tid / 12) * 12;
    const int wbase = o * 1728 + m1 * 144 + m2 * 12 + kz;
    float2 A0 = make_float2(0.f, 0.f), A1 = A0, A2 = A0, A3 = A0;
    for (int i = 0; i < 32; ++i) {
        float wr = wre[i * 55296 + wbase];
        float wi = wim[i * 55296 + wbase];
        float2 x0 = xs[i * 12 + kz];
        float2 x1 = xs[(32 + i) * 12 + kz];
        float2 x2 = xs[(64 + i) * 12 + kz];
        float2 x3 = xs[(96 + i) * 12 + kz];
        A0.x += x0.x * wr - x0.y * wi; A0.y += x0.x * wi + x0.y * wr;
        A1.x += x1.x * wr - x1.y * wi; A1.y += x1.x * wi + x1.y * wr;
        A2.x += x2.x * wr - x2.y * wi; A2.y += x2.x * wi + x2.y * wr;
        A3.x += x3.x * wr - x3.y * wi; A3.y += x3.x * wi + x3.y * wr;
    }
    F[(size_t)(0 * 32 + o) * 6912 + moff + kz] = A0;
    F[(size_t)(1 * 32 + o) * 6912 + moff + kz] = A1;
    F[(size_t)(2 * 32 + o) * 6912 + moff + kz] = A2;
    F[(size_t)(3 * 32 + o) * 6912 + moff + kz] = A3;
}

// ---------------------------------------------------------------------------
// Kernel 4: inverse DFT along H (24->64): output pairing h <-> 64-h composed
// with input-mode pairing ax <-> 24-ax; twiddles by recurrence (t <- t*W^hp).
// grid = B*O*24 = 3072, 256 threads. Y1[(bo*64+h)*288 + ay*12 + kz]
// ---------------------------------------------------------------------------
__global__ __launch_bounds__(256) void k_inv_x(const float2* __restrict__ F,
                                               float2* __restrict__ Y1) {
    __shared__ __align__(16) float2 fs[24 * 12];
    __shared__ float2 tw[64];
    const int tid = threadIdx.x;
    const int blk = blockIdx.x;
    const int ay = blk % 24, bo = blk / 24;
    fill_tw(tw, tid, 256);
    const float2* src = F + (size_t)bo * 6912 + ay * 12;
    for (int i4 = tid; i4 < 144; i4 += 256) {      // 24 rows * 6 float4
        int ax = i4 / 6, c4 = i4 - ax * 6;
        ((float4*)&fs[ax * 12])[c4] = ((const float4*)(src + (size_t)ax * 288))[c4];
    }
    __syncthreads();
    float2* dst = Y1 + (size_t)bo * (64 * 288) + ay * 12;
    // hp in 0..32: A -> h=hp; Bc -> h=64-hp (hp in 1..31).
    for (int idx = tid; idx < 396; idx += 256) {   // 33 hp * 12 kz
        int hp = idx / 12, kz = idx - (idx / 12) * 12;
        float2 f0  = fs[kz];
        float2 f12 = fs[12 * 12 + kz];
        float2 t12 = tw[(52 * hp) & 63];
        float2 A, Bc;
        A.x  = f0.x + f12.x * t12.x - f12.y * t12.y;
        A.y  = f0.y + f12.x * t12.y + f12.y * t12.x;
        Bc.x = f0.x + f12.x * t12.x + f12.y * t12.y;
        Bc.y = f0.y + f12.y * t12.x - f12.x * t12.y;
        const float2 u = tw[hp];         // hp <= 32 < 64
        float2 t = u;                    // t(a=1) = W^hp
        for (int a = 1; a <= 11; ++a) {
            float2 fa = fs[a * 12 + kz];
            float2 fb = fs[(24 - a) * 12 + kz];
            float Ex = fa.x + fb.x, Ey = fa.y + fb.y;
            float Ox = fa.x - fb.x, Oy = fa.y - fb.y;
            A.x  += t.x * Ex - t.y * Oy;  A.y  += t.x * Ey + t.y * Ox;
            Bc.x += t.x * Ex + t.y * Oy;  Bc.y += t.x * Ey - t.y * Ox;
            CMUL_STEP(t, u);
        }
        dst[hp * 288 + kz] = A;
        if (hp >= 1 && hp <= 31) dst[(64 - hp) * 288 + kz] = Bc;
    }
}

// ---------------------------------------------------------------------------
// Kernel 5: CFT branch — segment-0 Chebyshev (T0,T1,T2) + 3-freq rDFT over W.
// grid = B*C = 128 blocks, 256 threads = (q=w-group)*64 + d.
// cft[(b*64+d)*576 + c*18 + k*6 + f*2 + {re,im}]
// ---------------------------------------------------------------------------
__global__ __launch_bounds__(256) void k_cft(const float* __restrict__ x,
                                             float* __restrict__ cft) {
    __shared__ float2 tw[64];
    __shared__ float red[3 * 64 * 18];
    const int tid = threadIdx.x;
    const int blk = blockIdx.x;          // b*32 + c
    const int d = tid & 63, q = tid >> 6;
    fill_tw(tw, tid, 256);
    __syncthreads();
    float aR[3][3] = {{0.f}}, aI[3][3] = {{0.f}};
    const float* xb = x + (size_t)blk * 262144;
    for (int wi = 0; wi < 16; ++wi) {
        const int w = q * 16 + wi;
        float c0 = 0.f, c1 = 0.f, c2 = 0.f;
        #pragma unroll
        for (int s = 0; s < 8; ++s) {
            float xv = xb[(size_t)(s * 64 + w) * 64 + d];
            float t = (2.0f * (float)s - 7.0f) * (1.0f / 7.0f);
            c0 += xv;
            c1 += xv * t;
            c2 += xv * (2.0f * t * t - 1.0f);
        }
        c0 *= 0.125f; c1 *= 0.125f; c2 *= 0.125f;
        #pragma unroll
        for (int f = 0; f < 3; ++f) {
            float2 t = tw[(f * w) & 63];
            aR[0][f] += c0 * t.x; aI[0][f] -= c0 * t.y;
            aR[1][f] += c1 * t.x; aI[1][f] -= c1 * t.y;
            aR[2][f] += c2 * t.x; aI[2][f] -= c2 * t.y;
        }
    }
    if (q > 0) {
        float* dst = &red[((q - 1) * 64 + d) * 18];
        #pragma unroll
        for (int k = 0; k < 3; ++k)
            #pragma unroll
            for (int f = 0; f < 3; ++f) {
                dst[k * 6 + f * 2]     = aR[k][f];
                dst[k * 6 + f * 2 + 1] = aI[k][f];
            }
    }
    __syncthreads();
    if (q == 0) {
        #pragma unroll
        for (int qq = 0; qq < 3; ++qq) {
            const float* sr = &red[(qq * 64 + d) * 18];
            #pragma unroll
            for (int k = 0; k < 3; ++k)
                #pragma unroll
                for (int f = 0; f < 3; ++f) {
                    aR[k][f] += sr[k * 6 + f * 2];
                    aI[k][f] += sr[k * 6 + f * 2 + 1];
                }
        }
        const int b = blk >> 5, c = blk & 31;
        float* dst = cft + (size_t)(b * 64 + d) * 576 + c * 18;
        #pragma unroll
        for (int k = 0; k < 3; ++k)
            #pragma unroll
            for (int f = 0; f < 3; ++f) {
                dst[k * 6 + f * 2]     = aR[k][f];
                dst[k * 6 + f * 2 + 1] = aI[k][f];
            }
    }
}

// ---------------------------------------------------------------------------
// Kernel 6: MLP 576->128 (exact GeLU) ->32, pre-scaled by corr_scale.
// grid = B*D = 256 rows, 128 threads. corr[(b*32+o)*64 + d]
// ---------------------------------------------------------------------------
__global__ __launch_bounds__(128) void k_mlp(const float* __restrict__ cft,
                                             const float* __restrict__ w1,
                                             const float* __restrict__ b1,
                                             const float* __restrict__ w2,
                                             const float* __restrict__ b2,
                                             const float* __restrict__ cs,
                                             float* __restrict__ corr) {
    __shared__ float row[576];
    __shared__ float hbuf[128];
    const int n = blockIdx.x;            // b*64 + d
    const int tid = threadIdx.x;
    for (int i = tid; i < 576; i += 128) row[i] = cft[(size_t)n * 576 + i];
    __syncthreads();
    float acc = b1[tid];
    #pragma unroll 8
    for (int k = 0; k < 576; ++k) acc += row[k] * w1[k * 128 + tid];
    hbuf[tid] = 0.5f * acc * (1.0f + erff(acc * 0.70710678118654752f));
    __syncthreads();
    if (tid < 32) {
        float a2 = b2[tid];
        #pragma unroll 8
        for (int k = 0; k < 128; ++k) a2 += hbuf[k] * w2[k * 32 + tid];
        const int b = n >> 6, d = n & 63;
        corr[(b * 32 + tid) * 64 + d] = a2 * cs[0];
    }
}

// ---------------------------------------------------------------------------
// Kernel 7: fused inverse DFT along W (24->64) and D (12->64, c2r with c_kz),
// + correction add. grid = B*O*H = 8192, 256 threads.
// Stage A: mode-pair E/O + twiddle recurrence. Stage B: float4 y2 reads.
// ---------------------------------------------------------------------------
__global__ __launch_bounds__(256) void k_inv_yz(const float2* __restrict__ Y1,
                                                const float* __restrict__ corr,
                                                float* __restrict__ out) {
    __shared__ __align__(16) float2 y1[288];       // [a][kz]
    __shared__ __align__(16) float2 y2[64 * 12];   // [w][kz]
    __shared__ float2 tw[64];
    __shared__ float corrl[64];
    const int tid = threadIdx.x;
    const int blk = blockIdx.x;          // (b*32+o)*64 + h
    const int bo = blk >> 6;
    fill_tw(tw, tid, 256);
    {
        const float4* src4 = (const float4*)(Y1 + (size_t)blk * 288);
        for (int i4 = tid; i4 < 144; i4 += 256) ((float4*)y1)[i4] = src4[i4];
    }
    if (tid < 64) corrl[tid] = corr[bo * 64 + tid];
    __syncthreads();
    // stage A: W inverse, e^{+i 2pi ky w / 64}; thread = (w, kz-triplet).
    {
        const int w = tid >> 2, kz0 = (tid & 3) * 3;
        float2 a0 = make_float2(0.f, 0.f), a1 = a0, a2 = a0;
        {   // a = 0, ky = 0, t = (1,0)
            float2 f0 = y1[kz0], f1 = y1[kz0 + 1], f2 = y1[kz0 + 2];
            a0.x += f0.x; a0.y += f0.y;
            a1.x += f1.x; a1.y += f1.y;
            a2.x += f2.x; a2.y += f2.y;
        }
        {   // a = 12, ky = 52
            float2 t = tw[(52 * w) & 63];
            float2 f0 = y1[144 + kz0], f1 = y1[144 + kz0 + 1], f2 = y1[144 + kz0 + 2];
            a0.x += f0.x * t.x - f0.y * t.y; a0.y += f0.x * t.y + f0.y * t.x;
            a1.x += f1.x * t.x - f1.y * t.y; a1.y += f1.x * t.y + f1.y * t.x;
            a2.x += f2.x * t.x - f2.y * t.y; a2.y += f2.x * t.y + f2.y * t.x;
        }
        const float2 u = tw[w];
        float2 t = u;                    // t(a=1) = W^w
        for (int a = 1; a <= 11; ++a) {
            const float2* fa = &y1[a * 12 + kz0];
            const float2* fb = &y1[(24 - a) * 12 + kz0];
            float2 p0 = fa[0], p1 = fa[1], p2 = fa[2];
            float2 q0 = fb[0], q1 = fb[1], q2 = fb[2];
            float Ex, Ey, Ox, Oy;
            Ex = p0.x + q0.x; Ey = p0.y + q0.y; Ox = p0.x - q0.x; Oy = p0.y - q0.y;
            a0.x += t.x * Ex - t.y * Oy; a0.y += t.x * Ey + t.y * Ox;
            Ex = p1.x + q1.x; Ey = p1.y + q1.y; Ox = p1.x - q1.x; Oy = p1.y - q1.y;
            a1.x += t.x * Ex - t.y * Oy; a1.y += t.x * Ey + t.y * Ox;
            Ex = p2.x + q2.x; Ey = p2.y + q2.y; Ox = p2.x - q2.x; Oy = p2.y - q2.y;
            a2.x += t.x * Ex - t.y * Oy; a2.y += t.x * Ey + t.y * Ox;
            CMUL_STEP(t, u);
        }
        y2[w * 12 + kz0]     = a0;
        y2[w * 12 + kz0 + 1] = a1;
        y2[w * 12 + kz0 + 2] = a2;
    }
    // per-thread fixed d: hoist the 12 D-twiddles (scaled) into registers
    float ctw[12], stw[12];
    const int d = tid & 63;
    #pragma unroll
    for (int kz = 0; kz < 12; ++kz) {
        float2 t = tw[(kz * d) & 63];
        float sc = (kz == 0 ? 1.0f : 2.0f) * (1.0f / 262144.0f);
        ctw[kz] = t.x * sc;
        stw[kz] = t.y * sc;
    }
    __syncthreads();
    const float cv = corrl[d];
    float* orow = out + (size_t)blk * 4096;
    const int wq = tid >> 6;
    for (int r = 0; r < 16; ++r) {
        int w = r * 4 + wq;
        const float4* yv = (const float4*)&y2[w * 12];   // 12 float2 = 6 float4
        float4 p0 = yv[0], p1 = yv[1], p2 = yv[2];
        float4 p3 = yv[3], p4 = yv[4], p5 = yv[5];
        float s = cv;
        s += p0.x * ctw[0]  - p0.y * stw[0];
        s += p0.z * ctw[1]  - p0.w * stw[1];
        s += p1.x * ctw[2]  - p1.y * stw[2];
        s += p1.z * ctw[3]  - p1.w * stw[3];
        s += p2.x * ctw[4]  - p2.y * stw[4];
        s += p2.z * ctw[5]  - p2.w * stw[5];
        s += p3.x * ctw[6]  - p3.y * stw[6];
        s += p3.z * ctw[7]  - p3.w * stw[7];
        s += p4.x * ctw[8]  - p4.y * stw[8];
        s += p4.z * ctw[9]  - p4.w * stw[9];
        s += p5.x * ctw[10] - p5.y * stw[10];
        s += p5.z * ctw[11] - p5.w * stw[11];
        orow[w * 64 + d] = s;
    }
}

// ---------------------------------------------------------------------------
extern "C" void kernel_launch(void* const* d_in, const int* in_sizes, int n_in,
                              void* d_out, int out_size, void* d_ws, size_t ws_size,
                              hipStream_t stream) {
    const float* x    = (const float*)d_in[0];
    const float* w1re = (const float*)d_in[1];
    const float* w1im = (const float*)d_in[2];
    const float* w2re = (const float*)d_in[3];
    const float* w2im = (const float*)d_in[4];
    const float* w3re = (const float*)d_in[5];
    const float* w3im = (const float*)d_in[6];
    const float* w4re = (const float*)d_in[7];
    const float* w4im = (const float*)d_in[8];
    const float* mw1  = (const float*)d_in[9];
    const float* mb1  = (const float*)d_in[10];
    const float* mw2  = (const float*)d_in[11];
    const float* mb2  = (const float*)d_in[12];
    const float* cs   = (const float*)d_in[13];
    float* out = (float*)d_out;

    char* ws = (char*)d_ws;
    float2* X2   = (float2*)(ws);                 // 18,874,368 B  (reused as Y1)
    float2* X3   = (float2*)(ws + 18874368);      //  7,077,888 B
    float2* F    = (float2*)(ws + 25952256);      //  7,077,888 B
    float*  cft  = (float*) (ws + 33030144);      //    589,824 B
    float*  corr = (float*) (ws + 33619968);      //     32,768 B
    float2* Y1   = X2;                            // X2 dead after k_fwd_x

    hipLaunchKernelGGL(k_fwd_zy, dim3(8192), dim3(256), 0, stream, x, X2);
    hipLaunchKernelGGL(k_fwd_x,  dim3(3072), dim3(256), 0, stream, X2, X3);
    hipLaunchKernelGGL(k_mix,    dim3(576),  dim3(384), 0, stream, X3, F,
                       w1re, w1im, w2re, w2im, w3re, w3im, w4re, w4im);
    hipLaunchKernelGGL(k_inv_x,  dim3(3072), dim3(256), 0, stream, F, Y1);
    hipLaunchKernelGGL(k_cft,    dim3(128),  dim3(256), 0, stream, x, cft);
    hipLaunchKernelGGL(k_mlp,    dim3(256),  dim3(128), 0, stream,
                       cft, mw1, mb1, mw2, mb2, cs, corr);
    hipLaunchKernelGGL(k_inv_yz, dim3(8192), dim3(256), 0, stream, Y1, corr, out);
}